// Round 1
// baseline (2832.340 us; speedup 1.0000x reference)
//
#include <hip/hip_runtime.h>
#include <math.h>

#define NN 100000
#define NE 3200000

__device__ __forceinline__ float lrelu(float v) { return v >= 0.f ? v : 0.2f * v; }

// monotone float->uint mapping so atomicMax(uint) == float max; 0 is below all keys
__device__ __forceinline__ unsigned fkey(float f) {
  unsigned b = __float_as_uint(f);
  return (b & 0x80000000u) ? ~b : (b | 0x80000000u);
}
__device__ __forceinline__ float funkey(unsigned k) {
  return (k & 0x80000000u) ? __uint_as_float(k & 0x7FFFFFFFu) : __uint_as_float(~k);
}

// K1: [xl1 | xr1] = x @ [W1l | W1r]; x [N,256], each W [256,16]
__global__ __launch_bounds__(256) void k1_lin1(const float* __restrict__ x,
    const float* __restrict__ W1l, const float* __restrict__ W1r,
    float* __restrict__ xl1, float* __restrict__ xr1) {
  __shared__ float lw[256][32];
  int tid = threadIdx.x;
  for (int i = tid; i < 256 * 16; i += 256) {
    int k = i >> 4, c = i & 15;
    lw[k][c]      = W1l[i];
    lw[k][16 + c] = W1r[i];
  }
  __syncthreads();
  int row = blockIdx.x * 8 + (tid >> 5);
  if (row >= NN) return;
  int col = tid & 31;
  const float4* xrow = (const float4*)(x + (size_t)row * 256);
  float acc = 0.f;
  #pragma unroll 8
  for (int k4 = 0; k4 < 64; ++k4) {
    float4 xv = xrow[k4];
    int k = k4 << 2;
    acc = fmaf(xv.x, lw[k][col], acc);
    acc = fmaf(xv.y, lw[k + 1][col], acc);
    acc = fmaf(xv.z, lw[k + 2][col], acc);
    acc = fmaf(xv.w, lw[k + 3][col], acc);
  }
  if (col < 16) xl1[row * 16 + col] = acc;
  else          xr1[row * 16 + (col - 16)] = acc;
}

// layer-1 edge logit for (edge e, head h)
__device__ __forceinline__ float l1_logit(const float* __restrict__ xl1,
                                          const float* __restrict__ xr1,
                                          const float* __restrict__ a1,
                                          int s, int d, int h, float4& xl) {
  xl = *(const float4*)(xl1 + s * 16 + h * 4);
  float4 xr = *(const float4*)(xr1 + d * 16 + h * 4);
  float4 av = *(const float4*)(a1 + h * 4);
  return lrelu(xl.x + xr.x) * av.x + lrelu(xl.y + xr.y) * av.y +
         lrelu(xl.z + xr.z) * av.z + lrelu(xl.w + xr.w) * av.w;
}

__global__ __launch_bounds__(256) void k2_l1_max(const int* __restrict__ src, const int* __restrict__ dst,
    const float* __restrict__ xl1, const float* __restrict__ xr1,
    const float* __restrict__ a1, unsigned* __restrict__ m1) {
  int t = blockIdx.x * 256 + threadIdx.x;
  if (t >= NE * 4) return;
  int e = t >> 2, h = t & 3;
  int s = src[e], d = dst[e];
  float4 xl;
  float logit = l1_logit(xl1, xr1, a1, s, d, h, xl);
  atomicMax(&m1[d * 4 + h], fkey(logit));
}

__global__ __launch_bounds__(256) void k3_l1_den(const int* __restrict__ src, const int* __restrict__ dst,
    const float* __restrict__ xl1, const float* __restrict__ xr1,
    const float* __restrict__ a1, const unsigned* __restrict__ m1, float* __restrict__ den1) {
  int t = blockIdx.x * 256 + threadIdx.x;
  if (t >= NE * 4) return;
  int e = t >> 2, h = t & 3;
  int s = src[e], d = dst[e];
  float4 xl;
  float logit = l1_logit(xl1, xr1, a1, s, d, h, xl);
  float m = funkey(m1[d * 4 + h]);
  atomicAdd(&den1[d * 4 + h], expf(logit - m));
}

__global__ __launch_bounds__(256) void k4_l1_agg(const int* __restrict__ src, const int* __restrict__ dst,
    const float* __restrict__ xl1, const float* __restrict__ xr1,
    const float* __restrict__ a1, const unsigned* __restrict__ m1,
    const float* __restrict__ den1, float* __restrict__ out1) {
  int t = blockIdx.x * 256 + threadIdx.x;
  if (t >= NE * 4) return;
  int e = t >> 2, h = t & 3;
  int s = src[e], d = dst[e];
  float4 xl;
  float logit = l1_logit(xl1, xr1, a1, s, d, h, xl);
  float m = funkey(m1[d * 4 + h]);
  float alpha = expf(logit - m) / (den1[d * 4 + h] + 1e-16f);
  float* o = out1 + d * 16 + h * 4;
  atomicAdd(o + 0, alpha * xl.x);
  atomicAdd(o + 1, alpha * xl.y);
  atomicAdd(o + 2, alpha * xl.z);
  atomicAdd(o + 3, alpha * xl.w);
}

// K5: h = elu(out1 + b1); xl2 = h @ W2l; xr2 = h @ W2r   (16 -> 8 each)
__global__ __launch_bounds__(256) void k5_mid(const float* __restrict__ out1,
    const float* __restrict__ b1, const float* __restrict__ W2l, const float* __restrict__ W2r,
    float* __restrict__ xl2, float* __restrict__ xr2) {
  __shared__ float w2[16][16];  // cols 0..7 = W2l, 8..15 = W2r
  __shared__ float bb[16];
  int tid = threadIdx.x;
  if (tid < 128) {
    int k = tid >> 3, c = tid & 7;
    w2[k][c]     = W2l[tid];
    w2[k][8 + c] = W2r[tid];
  }
  if (tid < 16) bb[tid] = b1[tid];
  __syncthreads();
  int n = blockIdx.x * 256 + tid;
  if (n >= NN) return;
  float hbuf[16];
  const float4* orow = (const float4*)(out1 + n * 16);
  #pragma unroll
  for (int q = 0; q < 4; ++q) {
    float4 v = orow[q];
    float t0 = v.x + bb[q * 4 + 0];
    float t1 = v.y + bb[q * 4 + 1];
    float t2 = v.z + bb[q * 4 + 2];
    float t3 = v.w + bb[q * 4 + 3];
    hbuf[q * 4 + 0] = t0 > 0.f ? t0 : expm1f(t0);
    hbuf[q * 4 + 1] = t1 > 0.f ? t1 : expm1f(t1);
    hbuf[q * 4 + 2] = t2 > 0.f ? t2 : expm1f(t2);
    hbuf[q * 4 + 3] = t3 > 0.f ? t3 : expm1f(t3);
  }
  float al[8], ar[8];
  #pragma unroll
  for (int j = 0; j < 8; ++j) { al[j] = 0.f; ar[j] = 0.f; }
  #pragma unroll
  for (int k = 0; k < 16; ++k) {
    float hv = hbuf[k];
    #pragma unroll
    for (int j = 0; j < 8; ++j) {
      al[j] = fmaf(hv, w2[k][j], al[j]);
      ar[j] = fmaf(hv, w2[k][8 + j], ar[j]);
    }
  }
  *(float4*)(xl2 + n * 8)     = make_float4(al[0], al[1], al[2], al[3]);
  *(float4*)(xl2 + n * 8 + 4) = make_float4(al[4], al[5], al[6], al[7]);
  *(float4*)(xr2 + n * 8)     = make_float4(ar[0], ar[1], ar[2], ar[3]);
  *(float4*)(xr2 + n * 8 + 4) = make_float4(ar[4], ar[5], ar[6], ar[7]);
}

// layer-2 edge logit (H=1, C=8)
__device__ __forceinline__ float l2_logit(const float* __restrict__ xl2,
                                          const float* __restrict__ xr2,
                                          const float* __restrict__ a2,
                                          int s, int d, float4& l0, float4& l1) {
  l0 = *(const float4*)(xl2 + s * 8);
  l1 = *(const float4*)(xl2 + s * 8 + 4);
  float4 r0 = *(const float4*)(xr2 + d * 8);
  float4 r1 = *(const float4*)(xr2 + d * 8 + 4);
  float4 a0 = *(const float4*)(a2);
  float4 a1v = *(const float4*)(a2 + 4);
  return lrelu(l0.x + r0.x) * a0.x + lrelu(l0.y + r0.y) * a0.y +
         lrelu(l0.z + r0.z) * a0.z + lrelu(l0.w + r0.w) * a0.w +
         lrelu(l1.x + r1.x) * a1v.x + lrelu(l1.y + r1.y) * a1v.y +
         lrelu(l1.z + r1.z) * a1v.z + lrelu(l1.w + r1.w) * a1v.w;
}

__global__ __launch_bounds__(256) void k6_l2_max(const int* __restrict__ src, const int* __restrict__ dst,
    const float* __restrict__ xl2, const float* __restrict__ xr2,
    const float* __restrict__ a2, unsigned* __restrict__ m2) {
  int e = blockIdx.x * 256 + threadIdx.x;
  if (e >= NE) return;
  int s = src[e], d = dst[e];
  float4 l0, l1;
  float logit = l2_logit(xl2, xr2, a2, s, d, l0, l1);
  atomicMax(&m2[d], fkey(logit));
}

__global__ __launch_bounds__(256) void k7_l2_den(const int* __restrict__ src, const int* __restrict__ dst,
    const float* __restrict__ xl2, const float* __restrict__ xr2,
    const float* __restrict__ a2, const unsigned* __restrict__ m2, float* __restrict__ den2) {
  int e = blockIdx.x * 256 + threadIdx.x;
  if (e >= NE) return;
  int s = src[e], d = dst[e];
  float4 l0, l1;
  float logit = l2_logit(xl2, xr2, a2, s, d, l0, l1);
  float m = funkey(m2[d]);
  atomicAdd(&den2[d], expf(logit - m));
}

__global__ __launch_bounds__(256) void k8_l2_agg(const int* __restrict__ src, const int* __restrict__ dst,
    const float* __restrict__ xl2, const float* __restrict__ xr2,
    const float* __restrict__ a2, const unsigned* __restrict__ m2,
    const float* __restrict__ den2, float* __restrict__ out2) {
  int e = blockIdx.x * 256 + threadIdx.x;
  if (e >= NE) return;
  int s = src[e], d = dst[e];
  float4 l0, l1;
  float logit = l2_logit(xl2, xr2, a2, s, d, l0, l1);
  float m = funkey(m2[d]);
  float alpha = expf(logit - m) / (den2[d] + 1e-16f);
  float* o = out2 + d * 8;
  atomicAdd(o + 0, alpha * l0.x);
  atomicAdd(o + 1, alpha * l0.y);
  atomicAdd(o + 2, alpha * l0.z);
  atomicAdd(o + 3, alpha * l0.w);
  atomicAdd(o + 4, alpha * l1.x);
  atomicAdd(o + 5, alpha * l1.y);
  atomicAdd(o + 6, alpha * l1.z);
  atomicAdd(o + 7, alpha * l1.w);
}

// K9: out = sigmoid(out2 + b2)
__global__ __launch_bounds__(256) void k9_out(const float* __restrict__ out2,
    const float* __restrict__ b2, float* __restrict__ out) {
  int i = blockIdx.x * 256 + threadIdx.x;
  if (i >= NN * 8) return;
  float v = out2[i] + b2[i & 7];
  out[i] = 1.f / (1.f + expf(-v));
}

extern "C" void kernel_launch(void* const* d_in, const int* in_sizes, int n_in,
                              void* d_out, int out_size, void* d_ws, size_t ws_size,
                              hipStream_t stream) {
  const float* x   = (const float*)d_in[0];
  const int*   ei  = (const int*)d_in[1];
  const float* W1l = (const float*)d_in[2];
  const float* W1r = (const float*)d_in[3];
  const float* a1  = (const float*)d_in[4];
  const float* b1  = (const float*)d_in[5];
  const float* W2l = (const float*)d_in[6];
  const float* W2r = (const float*)d_in[7];
  const float* a2  = (const float*)d_in[8];
  const float* b2  = (const float*)d_in[9];
  const int* src = ei;
  const int* dst = ei + NE;

  char* ws = (char*)d_ws;
  size_t off = 0;
  auto alloc = [&](size_t nfloats) { void* p = (void*)(ws + off); off += nfloats * 4; return p; };
  // accumulators (must be zeroed every call)
  unsigned* m1  = (unsigned*)alloc((size_t)NN * 4);
  float*    den1= (float*)   alloc((size_t)NN * 4);
  float*    out1= (float*)   alloc((size_t)NN * 16);
  unsigned* m2  = (unsigned*)alloc((size_t)NN);
  float*    den2= (float*)   alloc((size_t)NN);
  float*    out2= (float*)   alloc((size_t)NN * 8);
  size_t accBytes = off;
  // scratch written before read
  float* xl1 = (float*)alloc((size_t)NN * 16);
  float* xr1 = (float*)alloc((size_t)NN * 16);
  float* xl2 = (float*)alloc((size_t)NN * 8);
  float* xr2 = (float*)alloc((size_t)NN * 8);

  hipMemsetAsync(d_ws, 0, accBytes, stream);

  k1_lin1<<<(NN + 7) / 8, 256, 0, stream>>>(x, W1l, W1r, xl1, xr1);

  int g4 = (NE * 4 + 255) / 256;
  k2_l1_max<<<g4, 256, 0, stream>>>(src, dst, xl1, xr1, a1, m1);
  k3_l1_den<<<g4, 256, 0, stream>>>(src, dst, xl1, xr1, a1, m1, den1);
  k4_l1_agg<<<g4, 256, 0, stream>>>(src, dst, xl1, xr1, a1, m1, den1, out1);

  k5_mid<<<(NN + 255) / 256, 256, 0, stream>>>(out1, b1, W2l, W2r, xl2, xr2);

  int g1 = (NE + 255) / 256;
  k6_l2_max<<<g1, 256, 0, stream>>>(src, dst, xl2, xr2, a2, m2);
  k7_l2_den<<<g1, 256, 0, stream>>>(src, dst, xl2, xr2, a2, m2, den2);
  k8_l2_agg<<<g1, 256, 0, stream>>>(src, dst, xl2, xr2, a2, m2, den2, out2);

  k9_out<<<(NN * 8 + 255) / 256, 256, 0, stream>>>(out2, b2, (float*)d_out);
}

// Round 2
// 794.377 us; speedup vs baseline: 3.5655x; 3.5655x over previous
//
#include <hip/hip_runtime.h>
#include <math.h>

#define NN 100000
#define NE 3200000
#define SCAN_CHUNK 1024
#define NCHUNK ((NN + SCAN_CHUNK - 1) / SCAN_CHUNK)   // 98

__device__ __forceinline__ float lrelu(float v) { return v >= 0.f ? v : 0.2f * v; }

// ---------------- CSR build: counting sort by dst ----------------

__global__ __launch_bounds__(256) void k_hist(const int* __restrict__ dst, int* __restrict__ cnt) {
  int t = blockIdx.x * 256 + threadIdx.x;
  if (t >= NE / 4) return;
  int4 d4 = ((const int4*)dst)[t];
  atomicAdd(&cnt[d4.x], 1);
  atomicAdd(&cnt[d4.y], 1);
  atomicAdd(&cnt[d4.z], 1);
  atomicAdd(&cnt[d4.w], 1);
}

__global__ __launch_bounds__(256) void k_scan1(const int* __restrict__ cnt,
    int* __restrict__ rowstart, int* __restrict__ blocksums) {
  __shared__ int sm[256];
  int tid = threadIdx.x;
  int base = blockIdx.x * SCAN_CHUNK + tid * 4;
  int c[4];
  #pragma unroll
  for (int k = 0; k < 4; ++k) c[k] = (base + k < NN) ? cnt[base + k] : 0;
  int s = c[0] + c[1] + c[2] + c[3];
  sm[tid] = s;
  __syncthreads();
  for (int off = 1; off < 256; off <<= 1) {
    int v = (tid >= off) ? sm[tid - off] : 0;
    __syncthreads();
    sm[tid] += v;
    __syncthreads();
  }
  int run = sm[tid] - s;   // exclusive prefix of this thread
  #pragma unroll
  for (int k = 0; k < 4; ++k) {
    if (base + k < NN) rowstart[base + k] = run;
    run += c[k];
  }
  if (tid == 255) blocksums[blockIdx.x] = sm[255];
}

__global__ __launch_bounds__(128) void k_scan2(const int* __restrict__ blocksums,
                                               int* __restrict__ blockoffs) {
  __shared__ int sm[128];
  int tid = threadIdx.x;
  int v = (tid < NCHUNK) ? blocksums[tid] : 0;
  sm[tid] = v;
  __syncthreads();
  for (int off = 1; off < 128; off <<= 1) {
    int u = (tid >= off) ? sm[tid - off] : 0;
    __syncthreads();
    sm[tid] += u;
    __syncthreads();
  }
  if (tid < NCHUNK) blockoffs[tid] = sm[tid] - v;
}

__global__ __launch_bounds__(256) void k_scan3(int* __restrict__ rowstart,
    const int* __restrict__ blockoffs, int* __restrict__ cursor) {
  int i = blockIdx.x * 256 + threadIdx.x;
  if (i >= NN) return;
  int r = rowstart[i] + blockoffs[i >> 10];
  rowstart[i] = r;
  cursor[i] = r;
}

__global__ __launch_bounds__(256) void k_scatter(const int* __restrict__ src,
    const int* __restrict__ dst, int* __restrict__ cursor, int* __restrict__ ssrc) {
  int t = blockIdx.x * 256 + threadIdx.x;
  if (t >= NE / 4) return;
  int4 s4 = ((const int4*)src)[t];
  int4 d4 = ((const int4*)dst)[t];
  int p;
  p = atomicAdd(&cursor[d4.x], 1); ssrc[p] = s4.x;
  p = atomicAdd(&cursor[d4.y], 1); ssrc[p] = s4.y;
  p = atomicAdd(&cursor[d4.z], 1); ssrc[p] = s4.z;
  p = atomicAdd(&cursor[d4.w], 1); ssrc[p] = s4.w;
}

// ---------------- K1: [xl1 | xr1] = x @ [W1l | W1r] ----------------

__global__ __launch_bounds__(256) void k1_lin1(const float* __restrict__ x,
    const float* __restrict__ W1l, const float* __restrict__ W1r,
    float* __restrict__ xl1, float* __restrict__ xr1) {
  __shared__ float lw[256][32];
  int tid = threadIdx.x;
  for (int i = tid; i < 256 * 16; i += 256) {
    int k = i >> 4, c = i & 15;
    lw[k][c]      = W1l[i];
    lw[k][16 + c] = W1r[i];
  }
  __syncthreads();
  int row = blockIdx.x * 8 + (tid >> 5);
  if (row >= NN) return;
  int col = tid & 31;
  const float4* xrow = (const float4*)(x + (size_t)row * 256);
  float acc = 0.f;
  #pragma unroll 8
  for (int k4 = 0; k4 < 64; ++k4) {
    float4 xv = xrow[k4];
    int k = k4 << 2;
    acc = fmaf(xv.x, lw[k][col], acc);
    acc = fmaf(xv.y, lw[k + 1][col], acc);
    acc = fmaf(xv.z, lw[k + 2][col], acc);
    acc = fmaf(xv.w, lw[k + 3][col], acc);
  }
  if (col < 16) xl1[row * 16 + col] = acc;
  else          xr1[row * 16 + (col - 16)] = acc;
}

// ---------------- Layer 1: per-node online softmax + fused elu/b1 + 16->8 transforms ----------------

__global__ __launch_bounds__(256) void k_l1(const float* __restrict__ xl1,
    const float* __restrict__ xr1, const float* __restrict__ a1,
    const float* __restrict__ b1, const float* __restrict__ W2l,
    const float* __restrict__ W2r, const int* __restrict__ rowstart,
    const int* __restrict__ cnt, const int* __restrict__ ssrc,
    float* __restrict__ xl2, float* __restrict__ xr2) {
  __shared__ float w2[16][16];   // cols 0..7 W2l, 8..15 W2r
  int tid = threadIdx.x;
  if (tid < 128) {
    int k = tid >> 3, c = tid & 7;
    w2[k][c]     = W2l[tid];
    w2[k][8 + c] = W2r[tid];
  }
  __syncthreads();
  int i = blockIdx.x * 256 + tid;
  if (i >= NN) return;

  float av[16];
  #pragma unroll
  for (int c = 0; c < 16; ++c) av[c] = a1[c];
  float xr[16];
  {
    const float4* xrp = (const float4*)(xr1 + (size_t)i * 16);
    #pragma unroll
    for (int q = 0; q < 4; ++q) *(float4*)&xr[q * 4] = xrp[q];
  }

  int rs = rowstart[i], deg = cnt[i];
  float m[4], den[4], acc[16];
  #pragma unroll
  for (int h = 0; h < 4; ++h) { m[h] = -INFINITY; den[h] = 0.f; }
  #pragma unroll
  for (int c = 0; c < 16; ++c) acc[c] = 0.f;

  float xn[16];
  if (deg > 0) {
    int s0 = ssrc[rs];
    const float4* xp = (const float4*)(xl1 + (size_t)s0 * 16);
    #pragma unroll
    for (int q = 0; q < 4; ++q) *(float4*)&xn[q * 4] = xp[q];
  }
  for (int j = 0; j < deg; ++j) {
    float xl[16];
    #pragma unroll
    for (int c = 0; c < 16; ++c) xl[c] = xn[c];
    if (j + 1 < deg) {
      int s = ssrc[rs + j + 1];
      const float4* xp = (const float4*)(xl1 + (size_t)s * 16);
      #pragma unroll
      for (int q = 0; q < 4; ++q) *(float4*)&xn[q * 4] = xp[q];
    }
    #pragma unroll
    for (int h = 0; h < 4; ++h) {
      float lg = lrelu(xl[h*4+0] + xr[h*4+0]) * av[h*4+0]
               + lrelu(xl[h*4+1] + xr[h*4+1]) * av[h*4+1]
               + lrelu(xl[h*4+2] + xr[h*4+2]) * av[h*4+2]
               + lrelu(xl[h*4+3] + xr[h*4+3]) * av[h*4+3];
      float nm = fmaxf(m[h], lg);
      float r = __expf(m[h] - nm);   // 0 on first edge (m=-inf), 1 if max unchanged
      float p = __expf(lg - nm);
      m[h] = nm;
      den[h] = den[h] * r + p;
      #pragma unroll
      for (int c = 0; c < 4; ++c)
        acc[h*4+c] = acc[h*4+c] * r + p * xl[h*4+c];
    }
  }

  // h = elu(acc/den + b1), then xl2 = h@W2l, xr2 = h@W2r
  float hh[16];
  #pragma unroll
  for (int c = 0; c < 16; ++c) {
    float v = acc[c] / (den[c >> 2] + 1e-16f) + b1[c];
    hh[c] = v > 0.f ? v : expm1f(v);
  }
  float ol[8], orr[8];
  #pragma unroll
  for (int j = 0; j < 8; ++j) { ol[j] = 0.f; orr[j] = 0.f; }
  #pragma unroll
  for (int k = 0; k < 16; ++k) {
    float hv = hh[k];
    #pragma unroll
    for (int j = 0; j < 8; ++j) {
      ol[j]  = fmaf(hv, w2[k][j], ol[j]);
      orr[j] = fmaf(hv, w2[k][8 + j], orr[j]);
    }
  }
  *(float4*)(xl2 + (size_t)i * 8)     = make_float4(ol[0], ol[1], ol[2], ol[3]);
  *(float4*)(xl2 + (size_t)i * 8 + 4) = make_float4(ol[4], ol[5], ol[6], ol[7]);
  *(float4*)(xr2 + (size_t)i * 8)     = make_float4(orr[0], orr[1], orr[2], orr[3]);
  *(float4*)(xr2 + (size_t)i * 8 + 4) = make_float4(orr[4], orr[5], orr[6], orr[7]);
}

// ---------------- Layer 2: per-node online softmax + fused sigmoid/b2 ----------------

__global__ __launch_bounds__(256) void k_l2(const float* __restrict__ xl2,
    const float* __restrict__ xr2, const float* __restrict__ a2,
    const float* __restrict__ b2, const int* __restrict__ rowstart,
    const int* __restrict__ cnt, const int* __restrict__ ssrc,
    float* __restrict__ out) {
  int i = blockIdx.x * 256 + threadIdx.x;
  if (i >= NN) return;

  float av[8];
  #pragma unroll
  for (int c = 0; c < 8; ++c) av[c] = a2[c];
  float xr[8];
  {
    const float4* xrp = (const float4*)(xr2 + (size_t)i * 8);
    *(float4*)&xr[0] = xrp[0];
    *(float4*)&xr[4] = xrp[1];
  }

  int rs = rowstart[i], deg = cnt[i];
  float m = -INFINITY, den = 0.f, acc[8];
  #pragma unroll
  for (int c = 0; c < 8; ++c) acc[c] = 0.f;

  float xn[8];
  if (deg > 0) {
    int s0 = ssrc[rs];
    const float4* xp = (const float4*)(xl2 + (size_t)s0 * 8);
    *(float4*)&xn[0] = xp[0];
    *(float4*)&xn[4] = xp[1];
  }
  for (int j = 0; j < deg; ++j) {
    float xl[8];
    #pragma unroll
    for (int c = 0; c < 8; ++c) xl[c] = xn[c];
    if (j + 1 < deg) {
      int s = ssrc[rs + j + 1];
      const float4* xp = (const float4*)(xl2 + (size_t)s * 8);
      *(float4*)&xn[0] = xp[0];
      *(float4*)&xn[4] = xp[1];
    }
    float lg = 0.f;
    #pragma unroll
    for (int c = 0; c < 8; ++c) lg += lrelu(xl[c] + xr[c]) * av[c];
    float nm = fmaxf(m, lg);
    float r = __expf(m - nm);
    float p = __expf(lg - nm);
    m = nm;
    den = den * r + p;
    #pragma unroll
    for (int c = 0; c < 8; ++c) acc[c] = acc[c] * r + p * xl[c];
  }

  float o[8];
  #pragma unroll
  for (int c = 0; c < 8; ++c) {
    float v = acc[c] / (den + 1e-16f) + b2[c];
    o[c] = 1.f / (1.f + __expf(-v));
  }
  *(float4*)(out + (size_t)i * 8)     = make_float4(o[0], o[1], o[2], o[3]);
  *(float4*)(out + (size_t)i * 8 + 4) = make_float4(o[4], o[5], o[6], o[7]);
}

// ---------------- launcher ----------------

extern "C" void kernel_launch(void* const* d_in, const int* in_sizes, int n_in,
                              void* d_out, int out_size, void* d_ws, size_t ws_size,
                              hipStream_t stream) {
  const float* x   = (const float*)d_in[0];
  const int*   ei  = (const int*)d_in[1];
  const float* W1l = (const float*)d_in[2];
  const float* W1r = (const float*)d_in[3];
  const float* a1  = (const float*)d_in[4];
  const float* b1  = (const float*)d_in[5];
  const float* W2l = (const float*)d_in[6];
  const float* W2r = (const float*)d_in[7];
  const float* a2  = (const float*)d_in[8];
  const float* b2  = (const float*)d_in[9];
  const int* src = ei;
  const int* dst = ei + NE;

  char* ws = (char*)d_ws;
  size_t off = 0;
  auto alloc = [&](size_t bytes) { void* p = (void*)(ws + off); off += bytes; return p; };
  int*   cnt       = (int*)alloc((size_t)NN * 4);
  int*   rowstart  = (int*)alloc((size_t)NN * 4);
  int*   cursor    = (int*)alloc((size_t)NN * 4);
  int*   blocksums = (int*)alloc(512);
  int*   blockoffs = (int*)alloc(512);
  int*   ssrc      = (int*)alloc((size_t)NE * 4);
  float* xl1       = (float*)alloc((size_t)NN * 16 * 4);
  float* xr1       = (float*)alloc((size_t)NN * 16 * 4);
  float* xl2       = (float*)alloc((size_t)NN * 8 * 4);
  float* xr2       = (float*)alloc((size_t)NN * 8 * 4);

  hipMemsetAsync(cnt, 0, (size_t)NN * 4, stream);

  k_hist   <<<(NE / 4 + 255) / 256, 256, 0, stream>>>(dst, cnt);
  k_scan1  <<<NCHUNK, 256, 0, stream>>>(cnt, rowstart, blocksums);
  k_scan2  <<<1, 128, 0, stream>>>(blocksums, blockoffs);
  k_scan3  <<<(NN + 255) / 256, 256, 0, stream>>>(rowstart, blockoffs, cursor);
  k_scatter<<<(NE / 4 + 255) / 256, 256, 0, stream>>>(src, dst, cursor, ssrc);

  k1_lin1<<<(NN + 7) / 8, 256, 0, stream>>>(x, W1l, W1r, xl1, xr1);

  int gn = (NN + 255) / 256;
  k_l1<<<gn, 256, 0, stream>>>(xl1, xr1, a1, b1, W2l, W2r, rowstart, cnt, ssrc, xl2, xr2);
  k_l2<<<gn, 256, 0, stream>>>(xl2, xr2, a2, b2, rowstart, cnt, ssrc, (float*)d_out);
}

// Round 3
// 504.623 us; speedup vs baseline: 5.6128x; 1.5742x over previous
//
#include <hip/hip_runtime.h>
#include <math.h>

#define NN 100000
#define NE 3200000
#define BW 512          // bucket width (nodes per bucket)
#define BSH 9           // log2(BW)
#define NB 196          // ceil(NN / BW)
#define EPB_A 8192      // edges per block in binning kernels
#define NBLK_A ((NE + EPB_A - 1) / EPB_A)   // 391

__device__ __forceinline__ float lrelu(float v) { return v >= 0.f ? v : 0.2f * v; }

// ---------------- CSR build: two-level bucket counting sort ----------------

__global__ __launch_bounds__(256) void k_bhist(const int* __restrict__ dst,
                                               unsigned* __restrict__ btot) {
  __shared__ unsigned lh[NB];
  int tid = threadIdx.x;
  if (tid < NB) lh[tid] = 0;
  __syncthreads();
  int base = blockIdx.x * EPB_A;
  int end = min(base + EPB_A, NE);
  for (int e = base + tid * 4; e < end; e += 1024) {
    int4 d4 = *(const int4*)(dst + e);
    atomicAdd(&lh[((unsigned)d4.x) >> BSH], 1u);
    atomicAdd(&lh[((unsigned)d4.y) >> BSH], 1u);
    atomicAdd(&lh[((unsigned)d4.z) >> BSH], 1u);
    atomicAdd(&lh[((unsigned)d4.w) >> BSH], 1u);
  }
  __syncthreads();
  if (tid < NB && lh[tid]) atomicAdd(&btot[tid], lh[tid]);
}

__global__ __launch_bounds__(256) void k_bscan(const unsigned* __restrict__ btot,
    unsigned* __restrict__ bstart, unsigned* __restrict__ bcur) {
  __shared__ unsigned sm[256];
  int tid = threadIdx.x;
  unsigned v = (tid < NB) ? btot[tid] : 0;
  sm[tid] = v;
  __syncthreads();
  for (int off = 1; off < 256; off <<= 1) {
    unsigned u = (tid >= off) ? sm[tid - off] : 0;
    __syncthreads();
    sm[tid] += u;
    __syncthreads();
  }
  unsigned exc = sm[tid] - v;
  if (tid < NB) { bstart[tid] = exc; bcur[tid] = exc; }
  if (tid == NB - 1) bstart[NB] = sm[tid];
}

__global__ __launch_bounds__(256) void k_bin(const int* __restrict__ src,
    const int* __restrict__ dst, unsigned* __restrict__ bcur,
    unsigned* __restrict__ abuf) {
  __shared__ unsigned lh[NB], gb[NB], lcur[NB];
  int tid = threadIdx.x;
  if (tid < NB) lh[tid] = 0;
  __syncthreads();
  int base = blockIdx.x * EPB_A;
  int end = min(base + EPB_A, NE);
  for (int e = base + tid * 4; e < end; e += 1024) {
    int4 d4 = *(const int4*)(dst + e);
    atomicAdd(&lh[((unsigned)d4.x) >> BSH], 1u);
    atomicAdd(&lh[((unsigned)d4.y) >> BSH], 1u);
    atomicAdd(&lh[((unsigned)d4.z) >> BSH], 1u);
    atomicAdd(&lh[((unsigned)d4.w) >> BSH], 1u);
  }
  __syncthreads();
  if (tid < NB) {
    unsigned c = lh[tid];
    gb[tid] = c ? atomicAdd(&bcur[tid], c) : 0u;
    lcur[tid] = 0;
  }
  __syncthreads();
  for (int e = base + tid * 4; e < end; e += 1024) {
    int4 d4 = *(const int4*)(dst + e);
    int4 s4 = *(const int4*)(src + e);
    #pragma unroll
    for (int k = 0; k < 4; ++k) {
      unsigned d = (unsigned)(&d4.x)[k];
      unsigned s = (unsigned)(&s4.x)[k];
      unsigned b = d >> BSH;
      unsigned p = gb[b] + atomicAdd(&lcur[b], 1u);
      abuf[p] = ((d & (BW - 1)) << 17) | s;
    }
  }
}

__global__ __launch_bounds__(256) void k_bsort(const unsigned* __restrict__ bstart,
    const unsigned* __restrict__ abuf, int* __restrict__ rowstart,
    int* __restrict__ cnt, int* __restrict__ ssrc) {
  __shared__ unsigned lh[BW];
  __shared__ unsigned lcur[BW];
  __shared__ unsigned sm[256];
  int b = blockIdx.x, tid = threadIdx.x;
  unsigned s0 = bstart[b], s1 = bstart[b + 1];
  lh[tid] = 0; lh[tid + 256] = 0;
  __syncthreads();
  for (unsigned i = s0 + tid; i < s1; i += 256)
    atomicAdd(&lh[abuf[i] >> 17], 1u);
  __syncthreads();
  unsigned a0 = lh[2 * tid], a1 = lh[2 * tid + 1];
  sm[tid] = a0 + a1;
  __syncthreads();
  for (int off = 1; off < 256; off <<= 1) {
    unsigned u = (tid >= off) ? sm[tid - off] : 0;
    __syncthreads();
    sm[tid] += u;
    __syncthreads();
  }
  unsigned exc = sm[tid] - (a0 + a1);
  int node = b * BW + 2 * tid;
  if (node < NN)     { rowstart[node]     = s0 + exc;      cnt[node]     = a0; }
  if (node + 1 < NN) { rowstart[node + 1] = s0 + exc + a0; cnt[node + 1] = a1; }
  lcur[2 * tid] = exc;
  lcur[2 * tid + 1] = exc + a0;
  __syncthreads();
  for (unsigned i = s0 + tid; i < s1; i += 256) {
    unsigned v = abuf[i];
    unsigned p = s0 + atomicAdd(&lcur[v >> 17], 1u);
    ssrc[p] = (int)(v & 0x1FFFFu);
  }
}

// ---------------- K1: [xl1 | xr1] = x @ [W1l | W1r] ----------------

__global__ __launch_bounds__(256) void k1_lin1(const float* __restrict__ x,
    const float* __restrict__ W1l, const float* __restrict__ W1r,
    float* __restrict__ xl1, float* __restrict__ xr1) {
  __shared__ float lw[256][32];
  int tid = threadIdx.x;
  for (int i = tid; i < 256 * 16; i += 256) {
    int k = i >> 4, c = i & 15;
    lw[k][c]      = W1l[i];
    lw[k][16 + c] = W1r[i];
  }
  __syncthreads();
  int row = blockIdx.x * 8 + (tid >> 5);
  if (row >= NN) return;
  int col = tid & 31;
  const float4* xrow = (const float4*)(x + (size_t)row * 256);
  float acc = 0.f;
  #pragma unroll 8
  for (int k4 = 0; k4 < 64; ++k4) {
    float4 xv = xrow[k4];
    int k = k4 << 2;
    acc = fmaf(xv.x, lw[k][col], acc);
    acc = fmaf(xv.y, lw[k + 1][col], acc);
    acc = fmaf(xv.z, lw[k + 2][col], acc);
    acc = fmaf(xv.w, lw[k + 3][col], acc);
  }
  if (col < 16) xl1[row * 16 + col] = acc;
  else          xr1[row * 16 + (col - 16)] = acc;
}

// ---------------- Layer 1: per-node online softmax + fused elu/b1 + 16->8 transforms ----------------

__global__ __launch_bounds__(256) void k_l1(const float* __restrict__ xl1,
    const float* __restrict__ xr1, const float* __restrict__ a1,
    const float* __restrict__ b1, const float* __restrict__ W2l,
    const float* __restrict__ W2r, const int* __restrict__ rowstart,
    const int* __restrict__ cnt, const int* __restrict__ ssrc,
    float* __restrict__ xl2, float* __restrict__ xr2) {
  __shared__ float w2[16][16];   // cols 0..7 W2l, 8..15 W2r
  int tid = threadIdx.x;
  if (tid < 128) {
    int k = tid >> 3, c = tid & 7;
    w2[k][c]     = W2l[tid];
    w2[k][8 + c] = W2r[tid];
  }
  __syncthreads();
  int i = blockIdx.x * 256 + tid;
  if (i >= NN) return;

  float av[16];
  #pragma unroll
  for (int c = 0; c < 16; ++c) av[c] = a1[c];
  float xr[16];
  {
    const float4* xrp = (const float4*)(xr1 + (size_t)i * 16);
    #pragma unroll
    for (int q = 0; q < 4; ++q) *(float4*)&xr[q * 4] = xrp[q];
  }

  int rs = rowstart[i], deg = cnt[i];
  float m[4], den[4], acc[16];
  #pragma unroll
  for (int h = 0; h < 4; ++h) { m[h] = -INFINITY; den[h] = 0.f; }
  #pragma unroll
  for (int c = 0; c < 16; ++c) acc[c] = 0.f;

  float xn[16];
  if (deg > 0) {
    int s0 = ssrc[rs];
    const float4* xp = (const float4*)(xl1 + (size_t)s0 * 16);
    #pragma unroll
    for (int q = 0; q < 4; ++q) *(float4*)&xn[q * 4] = xp[q];
  }
  for (int j = 0; j < deg; ++j) {
    float xl[16];
    #pragma unroll
    for (int c = 0; c < 16; ++c) xl[c] = xn[c];
    if (j + 1 < deg) {
      int s = ssrc[rs + j + 1];
      const float4* xp = (const float4*)(xl1 + (size_t)s * 16);
      #pragma unroll
      for (int q = 0; q < 4; ++q) *(float4*)&xn[q * 4] = xp[q];
    }
    #pragma unroll
    for (int h = 0; h < 4; ++h) {
      float lg = lrelu(xl[h*4+0] + xr[h*4+0]) * av[h*4+0]
               + lrelu(xl[h*4+1] + xr[h*4+1]) * av[h*4+1]
               + lrelu(xl[h*4+2] + xr[h*4+2]) * av[h*4+2]
               + lrelu(xl[h*4+3] + xr[h*4+3]) * av[h*4+3];
      float nm = fmaxf(m[h], lg);
      float r = __expf(m[h] - nm);
      float p = __expf(lg - nm);
      m[h] = nm;
      den[h] = den[h] * r + p;
      #pragma unroll
      for (int c = 0; c < 4; ++c)
        acc[h*4+c] = acc[h*4+c] * r + p * xl[h*4+c];
    }
  }

  float hh[16];
  #pragma unroll
  for (int c = 0; c < 16; ++c) {
    float v = acc[c] / (den[c >> 2] + 1e-16f) + b1[c];
    hh[c] = v > 0.f ? v : expm1f(v);
  }
  float ol[8], orr[8];
  #pragma unroll
  for (int j = 0; j < 8; ++j) { ol[j] = 0.f; orr[j] = 0.f; }
  #pragma unroll
  for (int k = 0; k < 16; ++k) {
    float hv = hh[k];
    #pragma unroll
    for (int j = 0; j < 8; ++j) {
      ol[j]  = fmaf(hv, w2[k][j], ol[j]);
      orr[j] = fmaf(hv, w2[k][8 + j], orr[j]);
    }
  }
  *(float4*)(xl2 + (size_t)i * 8)     = make_float4(ol[0], ol[1], ol[2], ol[3]);
  *(float4*)(xl2 + (size_t)i * 8 + 4) = make_float4(ol[4], ol[5], ol[6], ol[7]);
  *(float4*)(xr2 + (size_t)i * 8)     = make_float4(orr[0], orr[1], orr[2], orr[3]);
  *(float4*)(xr2 + (size_t)i * 8 + 4) = make_float4(orr[4], orr[5], orr[6], orr[7]);
}

// ---------------- Layer 2: per-node online softmax + fused sigmoid/b2 ----------------

__global__ __launch_bounds__(256) void k_l2(const float* __restrict__ xl2,
    const float* __restrict__ xr2, const float* __restrict__ a2,
    const float* __restrict__ b2, const int* __restrict__ rowstart,
    const int* __restrict__ cnt, const int* __restrict__ ssrc,
    float* __restrict__ out) {
  int i = blockIdx.x * 256 + threadIdx.x;
  if (i >= NN) return;

  float av[8];
  #pragma unroll
  for (int c = 0; c < 8; ++c) av[c] = a2[c];
  float xr[8];
  {
    const float4* xrp = (const float4*)(xr2 + (size_t)i * 8);
    *(float4*)&xr[0] = xrp[0];
    *(float4*)&xr[4] = xrp[1];
  }

  int rs = rowstart[i], deg = cnt[i];
  float m = -INFINITY, den = 0.f, acc[8];
  #pragma unroll
  for (int c = 0; c < 8; ++c) acc[c] = 0.f;

  float xn[8];
  if (deg > 0) {
    int s0 = ssrc[rs];
    const float4* xp = (const float4*)(xl2 + (size_t)s0 * 8);
    *(float4*)&xn[0] = xp[0];
    *(float4*)&xn[4] = xp[1];
  }
  for (int j = 0; j < deg; ++j) {
    float xl[8];
    #pragma unroll
    for (int c = 0; c < 8; ++c) xl[c] = xn[c];
    if (j + 1 < deg) {
      int s = ssrc[rs + j + 1];
      const float4* xp = (const float4*)(xl2 + (size_t)s * 8);
      *(float4*)&xn[0] = xp[0];
      *(float4*)&xn[4] = xp[1];
    }
    float lg = 0.f;
    #pragma unroll
    for (int c = 0; c < 8; ++c) lg += lrelu(xl[c] + xr[c]) * av[c];
    float nm = fmaxf(m, lg);
    float r = __expf(m - nm);
    float p = __expf(lg - nm);
    m = nm;
    den = den * r + p;
    #pragma unroll
    for (int c = 0; c < 8; ++c) acc[c] = acc[c] * r + p * xl[c];
  }

  float o[8];
  #pragma unroll
  for (int c = 0; c < 8; ++c) {
    float v = acc[c] / (den + 1e-16f) + b2[c];
    o[c] = 1.f / (1.f + __expf(-v));
  }
  *(float4*)(out + (size_t)i * 8)     = make_float4(o[0], o[1], o[2], o[3]);
  *(float4*)(out + (size_t)i * 8 + 4) = make_float4(o[4], o[5], o[6], o[7]);
}

// ---------------- launcher ----------------

extern "C" void kernel_launch(void* const* d_in, const int* in_sizes, int n_in,
                              void* d_out, int out_size, void* d_ws, size_t ws_size,
                              hipStream_t stream) {
  const float* x   = (const float*)d_in[0];
  const int*   ei  = (const int*)d_in[1];
  const float* W1l = (const float*)d_in[2];
  const float* W1r = (const float*)d_in[3];
  const float* a1  = (const float*)d_in[4];
  const float* b1  = (const float*)d_in[5];
  const float* W2l = (const float*)d_in[6];
  const float* W2r = (const float*)d_in[7];
  const float* a2  = (const float*)d_in[8];
  const float* b2  = (const float*)d_in[9];
  const int* src = ei;
  const int* dst = ei + NE;

  char* ws = (char*)d_ws;
  size_t off = 0;
  auto alloc = [&](size_t bytes) { void* p = (void*)(ws + off); off += (bytes + 255) & ~(size_t)255; return p; };
  unsigned* btot   = (unsigned*)alloc((size_t)NB * 4);
  unsigned* bstart = (unsigned*)alloc((size_t)(NB + 1) * 4);
  unsigned* bcur   = (unsigned*)alloc((size_t)NB * 4);
  int*      rowstart = (int*)alloc((size_t)NN * 4);
  int*      cnt      = (int*)alloc((size_t)NN * 4);
  int*      ssrc     = (int*)alloc((size_t)NE * 4);
  // abuf aliases xl1/xr1: abuf dead before k1_lin1 writes them
  char*     bigbase  = (char*)alloc((size_t)NN * 16 * 4 * 2);  // 12.8 MB
  unsigned* abuf = (unsigned*)bigbase;
  float*    xl1  = (float*)bigbase;
  float*    xr1  = (float*)(bigbase + (size_t)NN * 16 * 4);
  float*    xl2  = (float*)alloc((size_t)NN * 8 * 4);
  float*    xr2  = (float*)alloc((size_t)NN * 8 * 4);

  hipMemsetAsync(btot, 0, (size_t)NB * 4, stream);

  k_bhist<<<NBLK_A, 256, 0, stream>>>(dst, btot);
  k_bscan<<<1, 256, 0, stream>>>(btot, bstart, bcur);
  k_bin  <<<NBLK_A, 256, 0, stream>>>(src, dst, bcur, abuf);
  k_bsort<<<NB, 256, 0, stream>>>(bstart, abuf, rowstart, cnt, ssrc);

  k1_lin1<<<(NN + 7) / 8, 256, 0, stream>>>(x, W1l, W1r, xl1, xr1);

  int gn = (NN + 255) / 256;
  k_l1<<<gn, 256, 0, stream>>>(xl1, xr1, a1, b1, W2l, W2r, rowstart, cnt, ssrc, xl2, xr2);
  k_l2<<<gn, 256, 0, stream>>>(xl2, xr2, a2, b2, rowstart, cnt, ssrc, (float*)d_out);
}

// Round 4
// 433.481 us; speedup vs baseline: 6.5339x; 1.1641x over previous
//
#include <hip/hip_runtime.h>
#include <math.h>

#define NN 100000
#define NE 3200000
#define BW 512          // bucket width (nodes per bucket)
#define BSH 9           // log2(BW)
#define NB 196          // ceil(NN / BW)
#define EPB_A 8192      // edges per block in binning kernels
#define NBLK_A ((NE + EPB_A - 1) / EPB_A)   // 391

__device__ __forceinline__ float lrelu(float v) { return v >= 0.f ? v : 0.2f * v; }

// ---------------- CSR build: two-level bucket counting sort ----------------

__global__ __launch_bounds__(256) void k_bhist(const int* __restrict__ dst,
                                               unsigned* __restrict__ btot) {
  __shared__ unsigned lh[NB];
  int tid = threadIdx.x;
  if (tid < NB) lh[tid] = 0;
  __syncthreads();
  int base = blockIdx.x * EPB_A;
  int end = min(base + EPB_A, NE);
  for (int e = base + tid * 4; e < end; e += 1024) {
    int4 d4 = *(const int4*)(dst + e);
    atomicAdd(&lh[((unsigned)d4.x) >> BSH], 1u);
    atomicAdd(&lh[((unsigned)d4.y) >> BSH], 1u);
    atomicAdd(&lh[((unsigned)d4.z) >> BSH], 1u);
    atomicAdd(&lh[((unsigned)d4.w) >> BSH], 1u);
  }
  __syncthreads();
  if (tid < NB && lh[tid]) atomicAdd(&btot[tid], lh[tid]);
}

__global__ __launch_bounds__(256) void k_bscan(const unsigned* __restrict__ btot,
    unsigned* __restrict__ bstart, unsigned* __restrict__ bcur) {
  __shared__ unsigned sm[256];
  int tid = threadIdx.x;
  unsigned v = (tid < NB) ? btot[tid] : 0;
  sm[tid] = v;
  __syncthreads();
  for (int off = 1; off < 256; off <<= 1) {
    unsigned u = (tid >= off) ? sm[tid - off] : 0;
    __syncthreads();
    sm[tid] += u;
    __syncthreads();
  }
  unsigned exc = sm[tid] - v;
  if (tid < NB) { bstart[tid] = exc; bcur[tid] = exc; }
  if (tid == NB - 1) bstart[NB] = sm[tid];
}

__global__ __launch_bounds__(256) void k_bin(const int* __restrict__ src,
    const int* __restrict__ dst, unsigned* __restrict__ bcur,
    unsigned* __restrict__ abuf) {
  __shared__ unsigned lh[NB], gb[NB], lcur[NB];
  int tid = threadIdx.x;
  if (tid < NB) lh[tid] = 0;
  __syncthreads();
  int base = blockIdx.x * EPB_A;
  int end = min(base + EPB_A, NE);
  for (int e = base + tid * 4; e < end; e += 1024) {
    int4 d4 = *(const int4*)(dst + e);
    atomicAdd(&lh[((unsigned)d4.x) >> BSH], 1u);
    atomicAdd(&lh[((unsigned)d4.y) >> BSH], 1u);
    atomicAdd(&lh[((unsigned)d4.z) >> BSH], 1u);
    atomicAdd(&lh[((unsigned)d4.w) >> BSH], 1u);
  }
  __syncthreads();
  if (tid < NB) {
    unsigned c = lh[tid];
    gb[tid] = c ? atomicAdd(&bcur[tid], c) : 0u;
    lcur[tid] = 0;
  }
  __syncthreads();
  for (int e = base + tid * 4; e < end; e += 1024) {
    int4 d4 = *(const int4*)(dst + e);
    int4 s4 = *(const int4*)(src + e);
    #pragma unroll
    for (int k = 0; k < 4; ++k) {
      unsigned d = (unsigned)(&d4.x)[k];
      unsigned s = (unsigned)(&s4.x)[k];
      unsigned b = d >> BSH;
      unsigned p = gb[b] + atomicAdd(&lcur[b], 1u);
      abuf[p] = ((d & (BW - 1)) << 17) | s;
    }
  }
}

__global__ __launch_bounds__(256) void k_bsort(const unsigned* __restrict__ bstart,
    const unsigned* __restrict__ abuf, int* __restrict__ rowstart,
    int* __restrict__ cnt, int* __restrict__ ssrc) {
  __shared__ unsigned lh[BW];
  __shared__ unsigned lcur[BW];
  __shared__ unsigned sm[256];
  int b = blockIdx.x, tid = threadIdx.x;
  unsigned s0 = bstart[b], s1 = bstart[b + 1];
  lh[tid] = 0; lh[tid + 256] = 0;
  __syncthreads();
  for (unsigned i = s0 + tid; i < s1; i += 256)
    atomicAdd(&lh[abuf[i] >> 17], 1u);
  __syncthreads();
  unsigned a0 = lh[2 * tid], a1 = lh[2 * tid + 1];
  sm[tid] = a0 + a1;
  __syncthreads();
  for (int off = 1; off < 256; off <<= 1) {
    unsigned u = (tid >= off) ? sm[tid - off] : 0;
    __syncthreads();
    sm[tid] += u;
    __syncthreads();
  }
  unsigned exc = sm[tid] - (a0 + a1);
  int node = b * BW + 2 * tid;
  if (node < NN)     { rowstart[node]     = s0 + exc;      cnt[node]     = a0; }
  if (node + 1 < NN) { rowstart[node + 1] = s0 + exc + a0; cnt[node + 1] = a1; }
  lcur[2 * tid] = exc;
  lcur[2 * tid + 1] = exc + a0;
  __syncthreads();
  for (unsigned i = s0 + tid; i < s1; i += 256) {
    unsigned v = abuf[i];
    unsigned p = s0 + atomicAdd(&lcur[v >> 17], 1u);
    ssrc[p] = (int)(v & 0x1FFFFu);
  }
}

// ---------------- K1: [xl1 | xr1] = x @ [W1l | W1r] ----------------
// one thread per row; acc[32] in VGPRs; W read as wave-uniform ds_read_b128 (broadcast)

__global__ __launch_bounds__(256) void k1_lin1(const float* __restrict__ x,
    const float* __restrict__ W1l, const float* __restrict__ W1r,
    float* __restrict__ xl1, float* __restrict__ xr1) {
  __shared__ float lw[256][32];
  int tid = threadIdx.x;
  for (int i = tid; i < 256 * 16; i += 256) {
    int k = i >> 4, c = i & 15;
    lw[k][c]      = W1l[i];
    lw[k][16 + c] = W1r[i];
  }
  __syncthreads();
  int row = blockIdx.x * 256 + tid;
  if (row >= NN) return;
  const float4* xr4 = (const float4*)(x + (size_t)row * 256);

  float acc[32];
  #pragma unroll
  for (int c = 0; c < 32; ++c) acc[c] = 0.f;

  float4 va = xr4[0], vb = xr4[1];
  for (int k4 = 0; k4 < 64; k4 += 2) {
    float4 vc = xr4[(k4 + 2) & 63];
    float4 vd = xr4[(k4 + 3) & 63];
    #pragma unroll
    for (int half = 0; half < 2; ++half) {
      float4 v = half ? vb : va;
      int kb = (k4 + half) * 4;
      #pragma unroll
      for (int kk = 0; kk < 4; ++kk) {
        float xk = (&v.x)[kk];
        const float4* wrow = (const float4*)&lw[kb + kk][0];
        #pragma unroll
        for (int q = 0; q < 8; ++q) {
          float4 w = wrow[q];
          acc[q * 4 + 0] = fmaf(xk, w.x, acc[q * 4 + 0]);
          acc[q * 4 + 1] = fmaf(xk, w.y, acc[q * 4 + 1]);
          acc[q * 4 + 2] = fmaf(xk, w.z, acc[q * 4 + 2]);
          acc[q * 4 + 3] = fmaf(xk, w.w, acc[q * 4 + 3]);
        }
      }
    }
    va = vc; vb = vd;
  }
  float4* ol = (float4*)(xl1 + (size_t)row * 16);
  float4* orr = (float4*)(xr1 + (size_t)row * 16);
  #pragma unroll
  for (int q = 0; q < 4; ++q) {
    ol[q]  = make_float4(acc[q*4+0], acc[q*4+1], acc[q*4+2], acc[q*4+3]);
    orr[q] = make_float4(acc[16+q*4+0], acc[16+q*4+1], acc[16+q*4+2], acc[16+q*4+3]);
  }
}

// ---------------- Layer 1: warp-per-node; lane = (edge j<16, head h<4) ----------------

__global__ __launch_bounds__(256) void k_l1(const float* __restrict__ xl1,
    const float* __restrict__ xr1, const float* __restrict__ a1,
    const float* __restrict__ b1, const float* __restrict__ W2l,
    const float* __restrict__ W2r, const int* __restrict__ rowstart,
    const int* __restrict__ cnt, const int* __restrict__ ssrc,
    float* __restrict__ xl2, float* __restrict__ xr2) {
  __shared__ float w2[16][16];   // cols 0..7 W2l, 8..15 W2r
  int tid = threadIdx.x;
  if (tid < 128) {
    int k = tid >> 3, c = tid & 7;
    w2[k][c]     = W2l[tid];
    w2[k][8 + c] = W2r[tid];
  }
  __syncthreads();
  int i = (blockIdx.x * 256 + tid) >> 6;   // node = global warp id
  if (i >= NN) return;
  int lane = tid & 63;
  int j = lane >> 2, h = lane & 3;

  float4 xr = *(const float4*)(xr1 + (size_t)i * 16 + h * 4);
  float4 av = *(const float4*)(a1 + h * 4);
  int rs = rowstart[i], deg = cnt[i];

  float m = -INFINITY, den = 0.f;
  float4 acc = make_float4(0.f, 0.f, 0.f, 0.f);

  for (int base = 0; base < deg; base += 16) {
    int jj = base + j;
    bool valid = jj < deg;
    int s = valid ? ssrc[rs + jj] : 0;
    float4 xl = make_float4(0.f, 0.f, 0.f, 0.f);
    if (valid) xl = *(const float4*)(xl1 + (size_t)s * 16 + h * 4);
    float lg = valid ? (lrelu(xl.x + xr.x) * av.x + lrelu(xl.y + xr.y) * av.y +
                        lrelu(xl.z + xr.z) * av.z + lrelu(xl.w + xr.w) * av.w)
                     : -INFINITY;
    float mp = lg;
    mp = fmaxf(mp, __shfl_xor(mp, 4));
    mp = fmaxf(mp, __shfl_xor(mp, 8));
    mp = fmaxf(mp, __shfl_xor(mp, 16));
    mp = fmaxf(mp, __shfl_xor(mp, 32));
    float nm = fmaxf(m, mp);
    float r = __expf(m - nm);
    float p = __expf(lg - nm);
    m = nm;
    den = den * r + p;
    acc.x = acc.x * r + p * xl.x;
    acc.y = acc.y * r + p * xl.y;
    acc.z = acc.z * r + p * xl.z;
    acc.w = acc.w * r + p * xl.w;
  }
  // reduce den + acc over j (xor strides 4..32)
  #pragma unroll
  for (int st = 4; st <= 32; st <<= 1) {
    den   += __shfl_xor(den, st);
    acc.x += __shfl_xor(acc.x, st);
    acc.y += __shfl_xor(acc.y, st);
    acc.z += __shfl_xor(acc.z, st);
    acc.w += __shfl_xor(acc.w, st);
  }
  float4 bv = *(const float4*)(b1 + h * 4);
  float inv = 1.f / (den + 1e-16f);
  float q0 = acc.x * inv + bv.x;
  float q1 = acc.y * inv + bv.y;
  float q2 = acc.z * inv + bv.z;
  float q3 = acc.w * inv + bv.w;
  q0 = q0 > 0.f ? q0 : expm1f(q0);
  q1 = q1 > 0.f ? q1 : expm1f(q1);
  q2 = q2 > 0.f ? q2 : expm1f(q2);
  q3 = q3 > 0.f ? q3 : expm1f(q3);

  // gather hh[16] on every lane (source lanes 0..3 hold head quads)
  float hh[16];
  #pragma unroll
  for (int hp = 0; hp < 4; ++hp) {
    hh[hp * 4 + 0] = __shfl(q0, hp);
    hh[hp * 4 + 1] = __shfl(q1, hp);
    hh[hp * 4 + 2] = __shfl(q2, hp);
    hh[hp * 4 + 3] = __shfl(q3, hp);
  }
  int t = lane & 15;
  float val = 0.f;
  #pragma unroll
  for (int k = 0; k < 16; ++k) val = fmaf(hh[k], w2[k][t], val);
  if (lane < 8)       xl2[(size_t)i * 8 + lane] = val;
  else if (lane < 16) xr2[(size_t)i * 8 + (lane - 8)] = val;
}

// ---------------- Layer 2: warp-per-node; lane = edge slot (64/pass) ----------------

__global__ __launch_bounds__(256) void k_l2(const float* __restrict__ xl2,
    const float* __restrict__ xr2, const float* __restrict__ a2,
    const float* __restrict__ b2, const int* __restrict__ rowstart,
    const int* __restrict__ cnt, const int* __restrict__ ssrc,
    float* __restrict__ out) {
  int tid = threadIdx.x;
  int i = (blockIdx.x * 256 + tid) >> 6;
  if (i >= NN) return;
  int lane = tid & 63;

  float xr[8], av[8];
  *(float4*)&xr[0] = *(const float4*)(xr2 + (size_t)i * 8);
  *(float4*)&xr[4] = *(const float4*)(xr2 + (size_t)i * 8 + 4);
  *(float4*)&av[0] = *(const float4*)(a2);
  *(float4*)&av[4] = *(const float4*)(a2 + 4);
  int rs = rowstart[i], deg = cnt[i];

  float m = -INFINITY, den = 0.f, acc[8];
  #pragma unroll
  for (int c = 0; c < 8; ++c) acc[c] = 0.f;

  for (int base = 0; base < deg; base += 64) {
    int jj = base + lane;
    bool valid = jj < deg;
    int s = valid ? ssrc[rs + jj] : 0;
    float xl[8];
    #pragma unroll
    for (int c = 0; c < 8; ++c) xl[c] = 0.f;
    if (valid) {
      *(float4*)&xl[0] = *(const float4*)(xl2 + (size_t)s * 8);
      *(float4*)&xl[4] = *(const float4*)(xl2 + (size_t)s * 8 + 4);
    }
    float lg;
    if (valid) {
      lg = 0.f;
      #pragma unroll
      for (int c = 0; c < 8; ++c) lg += lrelu(xl[c] + xr[c]) * av[c];
    } else lg = -INFINITY;
    float mp = lg;
    #pragma unroll
    for (int st = 1; st <= 32; st <<= 1) mp = fmaxf(mp, __shfl_xor(mp, st));
    float nm = fmaxf(m, mp);
    float r = __expf(m - nm);
    float p = __expf(lg - nm);
    m = nm;
    den = den * r + p;
    #pragma unroll
    for (int c = 0; c < 8; ++c) acc[c] = acc[c] * r + p * xl[c];
  }
  #pragma unroll
  for (int st = 1; st <= 32; st <<= 1) {
    den += __shfl_xor(den, st);
    #pragma unroll
    for (int c = 0; c < 8; ++c) acc[c] += __shfl_xor(acc[c], st);
  }
  if (lane == 0) {
    float inv = 1.f / (den + 1e-16f);
    float o[8];
    #pragma unroll
    for (int c = 0; c < 8; ++c) {
      float v = acc[c] * inv + b2[c];
      o[c] = 1.f / (1.f + __expf(-v));
    }
    *(float4*)(out + (size_t)i * 8)     = make_float4(o[0], o[1], o[2], o[3]);
    *(float4*)(out + (size_t)i * 8 + 4) = make_float4(o[4], o[5], o[6], o[7]);
  }
}

// ---------------- launcher ----------------

extern "C" void kernel_launch(void* const* d_in, const int* in_sizes, int n_in,
                              void* d_out, int out_size, void* d_ws, size_t ws_size,
                              hipStream_t stream) {
  const float* x   = (const float*)d_in[0];
  const int*   ei  = (const int*)d_in[1];
  const float* W1l = (const float*)d_in[2];
  const float* W1r = (const float*)d_in[3];
  const float* a1  = (const float*)d_in[4];
  const float* b1  = (const float*)d_in[5];
  const float* W2l = (const float*)d_in[6];
  const float* W2r = (const float*)d_in[7];
  const float* a2  = (const float*)d_in[8];
  const float* b2  = (const float*)d_in[9];
  const int* src = ei;
  const int* dst = ei + NE;

  char* ws = (char*)d_ws;
  size_t off = 0;
  auto alloc = [&](size_t bytes) { void* p = (void*)(ws + off); off += (bytes + 255) & ~(size_t)255; return p; };
  unsigned* btot   = (unsigned*)alloc((size_t)NB * 4);
  unsigned* bstart = (unsigned*)alloc((size_t)(NB + 1) * 4);
  unsigned* bcur   = (unsigned*)alloc((size_t)NB * 4);
  int*      rowstart = (int*)alloc((size_t)NN * 4);
  int*      cnt      = (int*)alloc((size_t)NN * 4);
  int*      ssrc     = (int*)alloc((size_t)NE * 4);
  // abuf aliases xl1/xr1: abuf dead before k1_lin1 writes them
  char*     bigbase  = (char*)alloc((size_t)NN * 16 * 4 * 2);  // 12.8 MB
  unsigned* abuf = (unsigned*)bigbase;
  float*    xl1  = (float*)bigbase;
  float*    xr1  = (float*)(bigbase + (size_t)NN * 16 * 4);
  float*    xl2  = (float*)alloc((size_t)NN * 8 * 4);
  float*    xr2  = (float*)alloc((size_t)NN * 8 * 4);

  hipMemsetAsync(btot, 0, (size_t)NB * 4, stream);

  k_bhist<<<NBLK_A, 256, 0, stream>>>(dst, btot);
  k_bscan<<<1, 256, 0, stream>>>(btot, bstart, bcur);
  k_bin  <<<NBLK_A, 256, 0, stream>>>(src, dst, bcur, abuf);
  k_bsort<<<NB, 256, 0, stream>>>(bstart, abuf, rowstart, cnt, ssrc);

  k1_lin1<<<(NN + 255) / 256, 256, 0, stream>>>(x, W1l, W1r, xl1, xr1);

  int gw = (NN * 64 + 255) / 256;   // warp-per-node
  k_l1<<<gw, 256, 0, stream>>>(xl1, xr1, a1, b1, W2l, W2r, rowstart, cnt, ssrc, xl2, xr2);
  k_l2<<<gw, 256, 0, stream>>>(xl2, xr2, a2, b2, rowstart, cnt, ssrc, (float*)d_out);
}

// Round 5
// 412.761 us; speedup vs baseline: 6.8619x; 1.0502x over previous
//
#include <hip/hip_runtime.h>
#include <math.h>

#define NN 100000
#define NE 3200000
#define BW 512          // bucket width (nodes per bucket)
#define BSH 9           // log2(BW)
#define NB 196          // ceil(NN / BW)
#define EPB_A 8192      // edges per block in binning kernels
#define NBLK_A ((NE + EPB_A - 1) / EPB_A)   // 391

__device__ __forceinline__ float lrelu(float v) { return v >= 0.f ? v : 0.2f * v; }

// ---------------- CSR build: two-level bucket counting sort ----------------

__global__ __launch_bounds__(256) void k_bhist(const int* __restrict__ dst,
                                               unsigned* __restrict__ btot) {
  __shared__ unsigned lh[NB];
  int tid = threadIdx.x;
  if (tid < NB) lh[tid] = 0;
  __syncthreads();
  int base = blockIdx.x * EPB_A;
  int end = min(base + EPB_A, NE);
  for (int e = base + tid * 4; e < end; e += 1024) {
    int4 d4 = *(const int4*)(dst + e);
    atomicAdd(&lh[((unsigned)d4.x) >> BSH], 1u);
    atomicAdd(&lh[((unsigned)d4.y) >> BSH], 1u);
    atomicAdd(&lh[((unsigned)d4.z) >> BSH], 1u);
    atomicAdd(&lh[((unsigned)d4.w) >> BSH], 1u);
  }
  __syncthreads();
  if (tid < NB && lh[tid]) atomicAdd(&btot[tid], lh[tid]);
}

__global__ __launch_bounds__(256) void k_bscan(const unsigned* __restrict__ btot,
    unsigned* __restrict__ bstart, unsigned* __restrict__ bcur) {
  __shared__ unsigned sm[256];
  int tid = threadIdx.x;
  unsigned v = (tid < NB) ? btot[tid] : 0;
  sm[tid] = v;
  __syncthreads();
  for (int off = 1; off < 256; off <<= 1) {
    unsigned u = (tid >= off) ? sm[tid - off] : 0;
    __syncthreads();
    sm[tid] += u;
    __syncthreads();
  }
  unsigned exc = sm[tid] - v;
  if (tid < NB) { bstart[tid] = exc; bcur[tid] = exc; }
  if (tid == NB - 1) bstart[NB] = sm[tid];
}

__global__ __launch_bounds__(256) void k_bin(const int* __restrict__ src,
    const int* __restrict__ dst, unsigned* __restrict__ bcur,
    unsigned* __restrict__ abuf) {
  __shared__ unsigned lh[NB], gb[NB], lcur[NB];
  int tid = threadIdx.x;
  if (tid < NB) lh[tid] = 0;
  __syncthreads();
  int base = blockIdx.x * EPB_A;
  int end = min(base + EPB_A, NE);
  for (int e = base + tid * 4; e < end; e += 1024) {
    int4 d4 = *(const int4*)(dst + e);
    atomicAdd(&lh[((unsigned)d4.x) >> BSH], 1u);
    atomicAdd(&lh[((unsigned)d4.y) >> BSH], 1u);
    atomicAdd(&lh[((unsigned)d4.z) >> BSH], 1u);
    atomicAdd(&lh[((unsigned)d4.w) >> BSH], 1u);
  }
  __syncthreads();
  if (tid < NB) {
    unsigned c = lh[tid];
    gb[tid] = c ? atomicAdd(&bcur[tid], c) : 0u;
    lcur[tid] = 0;
  }
  __syncthreads();
  for (int e = base + tid * 4; e < end; e += 1024) {
    int4 d4 = *(const int4*)(dst + e);
    int4 s4 = *(const int4*)(src + e);
    #pragma unroll
    for (int k = 0; k < 4; ++k) {
      unsigned d = (unsigned)(&d4.x)[k];
      unsigned s = (unsigned)(&s4.x)[k];
      unsigned b = d >> BSH;
      unsigned p = gb[b] + atomicAdd(&lcur[b], 1u);
      abuf[p] = ((d & (BW - 1)) << 17) | s;
    }
  }
}

__global__ __launch_bounds__(256) void k_bsort(const unsigned* __restrict__ bstart,
    const unsigned* __restrict__ abuf, int* __restrict__ rowstart,
    int* __restrict__ cnt, int* __restrict__ ssrc) {
  __shared__ unsigned lh[BW];
  __shared__ unsigned lcur[BW];
  __shared__ unsigned sm[256];
  int b = blockIdx.x, tid = threadIdx.x;
  unsigned s0 = bstart[b], s1 = bstart[b + 1];
  lh[tid] = 0; lh[tid + 256] = 0;
  __syncthreads();
  for (unsigned i = s0 + tid; i < s1; i += 256)
    atomicAdd(&lh[abuf[i] >> 17], 1u);
  __syncthreads();
  unsigned a0 = lh[2 * tid], a1 = lh[2 * tid + 1];
  sm[tid] = a0 + a1;
  __syncthreads();
  for (int off = 1; off < 256; off <<= 1) {
    unsigned u = (tid >= off) ? sm[tid - off] : 0;
    __syncthreads();
    sm[tid] += u;
    __syncthreads();
  }
  unsigned exc = sm[tid] - (a0 + a1);
  int node = b * BW + 2 * tid;
  if (node < NN)     { rowstart[node]     = s0 + exc;      cnt[node]     = a0; }
  if (node + 1 < NN) { rowstart[node + 1] = s0 + exc + a0; cnt[node + 1] = a1; }
  lcur[2 * tid] = exc;
  lcur[2 * tid + 1] = exc + a0;
  __syncthreads();
  for (unsigned i = s0 + tid; i < s1; i += 256) {
    unsigned v = abuf[i];
    unsigned p = s0 + atomicAdd(&lcur[v >> 17], 1u);
    ssrc[p] = (int)(v & 0x1FFFFu);
  }
}

// ---------------- K1: [xl1 | xr1] = x @ [W1l | W1r] ----------------

__global__ __launch_bounds__(256) void k1_lin1(const float* __restrict__ x,
    const float* __restrict__ W1l, const float* __restrict__ W1r,
    float* __restrict__ xl1, float* __restrict__ xr1) {
  __shared__ float lw[256][32];
  int tid = threadIdx.x;
  for (int i = tid; i < 256 * 16; i += 256) {
    int k = i >> 4, c = i & 15;
    lw[k][c]      = W1l[i];
    lw[k][16 + c] = W1r[i];
  }
  __syncthreads();
  int row = blockIdx.x * 256 + tid;
  if (row >= NN) return;
  const float4* xr4 = (const float4*)(x + (size_t)row * 256);

  float acc[32];
  #pragma unroll
  for (int c = 0; c < 32; ++c) acc[c] = 0.f;

  float4 va = xr4[0], vb = xr4[1];
  for (int k4 = 0; k4 < 64; k4 += 2) {
    float4 vc = xr4[(k4 + 2) & 63];
    float4 vd = xr4[(k4 + 3) & 63];
    #pragma unroll
    for (int half = 0; half < 2; ++half) {
      float4 v = half ? vb : va;
      int kb = (k4 + half) * 4;
      #pragma unroll
      for (int kk = 0; kk < 4; ++kk) {
        float xk = (&v.x)[kk];
        const float4* wrow = (const float4*)&lw[kb + kk][0];
        #pragma unroll
        for (int q = 0; q < 8; ++q) {
          float4 w = wrow[q];
          acc[q * 4 + 0] = fmaf(xk, w.x, acc[q * 4 + 0]);
          acc[q * 4 + 1] = fmaf(xk, w.y, acc[q * 4 + 1]);
          acc[q * 4 + 2] = fmaf(xk, w.z, acc[q * 4 + 2]);
          acc[q * 4 + 3] = fmaf(xk, w.w, acc[q * 4 + 3]);
        }
      }
    }
    va = vc; vb = vd;
  }
  float4* ol = (float4*)(xl1 + (size_t)row * 16);
  float4* orr = (float4*)(xr1 + (size_t)row * 16);
  #pragma unroll
  for (int q = 0; q < 4; ++q) {
    ol[q]  = make_float4(acc[q*4+0], acc[q*4+1], acc[q*4+2], acc[q*4+3]);
    orr[q] = make_float4(acc[16+q*4+0], acc[16+q*4+1], acc[16+q*4+2], acc[16+q*4+3]);
  }
}

// ---------------- Layer 1: warp-per-node, no-max softmax, writes elu'd h ----------------

__global__ __launch_bounds__(256) void k_l1(const float* __restrict__ xl1,
    const float* __restrict__ xr1, const float* __restrict__ a1,
    const float* __restrict__ b1, const int* __restrict__ rowstart,
    const int* __restrict__ cnt, const int* __restrict__ ssrc,
    float* __restrict__ hbuf) {
  int tid = threadIdx.x;
  int i = (blockIdx.x * 256 + tid) >> 6;
  if (i >= NN) return;
  int lane = tid & 63;
  int j = lane >> 2, h = lane & 3;

  float4 xr = *(const float4*)(xr1 + (size_t)i * 16 + h * 4);
  float4 av = *(const float4*)(a1 + h * 4);
  int rs = rowstart[i], deg = cnt[i];

  float den = 0.f;
  float4 acc = make_float4(0.f, 0.f, 0.f, 0.f);

  for (int base = 0; base < deg; base += 16) {
    int jj = base + j;
    bool valid = jj < deg;
    int s = valid ? ssrc[rs + jj] : 0;
    float4 xl = *(const float4*)(xl1 + (size_t)s * 16 + h * 4);
    float lg = lrelu(xl.x + xr.x) * av.x + lrelu(xl.y + xr.y) * av.y +
               lrelu(xl.z + xr.z) * av.z + lrelu(xl.w + xr.w) * av.w;
    float p = valid ? __expf(lg) : 0.f;
    den += p;
    acc.x = fmaf(p, xl.x, acc.x);
    acc.y = fmaf(p, xl.y, acc.y);
    acc.z = fmaf(p, xl.z, acc.z);
    acc.w = fmaf(p, xl.w, acc.w);
  }
  #pragma unroll
  for (int st = 4; st <= 32; st <<= 1) {
    den   += __shfl_xor(den, st);
    acc.x += __shfl_xor(acc.x, st);
    acc.y += __shfl_xor(acc.y, st);
    acc.z += __shfl_xor(acc.z, st);
    acc.w += __shfl_xor(acc.w, st);
  }
  if (j == 0) {
    float inv = 1.f / (den + 1e-16f);
    float4 bv = *(const float4*)(b1 + h * 4);
    float v0 = fmaf(acc.x, inv, bv.x);
    float v1 = fmaf(acc.y, inv, bv.y);
    float v2 = fmaf(acc.z, inv, bv.z);
    float v3 = fmaf(acc.w, inv, bv.w);
    v0 = v0 > 0.f ? v0 : __expf(v0) - 1.f;
    v1 = v1 > 0.f ? v1 : __expf(v1) - 1.f;
    v2 = v2 > 0.f ? v2 : __expf(v2) - 1.f;
    v3 = v3 > 0.f ? v3 : __expf(v3) - 1.f;
    *(float4*)(hbuf + (size_t)i * 16 + h * 4) = make_float4(v0, v1, v2, v3);
  }
}

// ---------------- K5: xl2 = h @ W2l, xr2 = h @ W2r (h already elu'd) ----------------

__global__ __launch_bounds__(256) void k5_mid(const float* __restrict__ hbuf,
    const float* __restrict__ W2l, const float* __restrict__ W2r,
    float* __restrict__ xl2, float* __restrict__ xr2) {
  __shared__ float w2[16][16];  // cols 0..7 = W2l, 8..15 = W2r
  int tid = threadIdx.x;
  if (tid < 128) {
    int k = tid >> 3, c = tid & 7;
    w2[k][c]     = W2l[tid];
    w2[k][8 + c] = W2r[tid];
  }
  __syncthreads();
  int n = blockIdx.x * 256 + tid;
  if (n >= NN) return;
  float hh[16];
  const float4* hp = (const float4*)(hbuf + (size_t)n * 16);
  #pragma unroll
  for (int q = 0; q < 4; ++q) *(float4*)&hh[q * 4] = hp[q];
  float ol[8], orr[8];
  #pragma unroll
  for (int jq = 0; jq < 8; ++jq) { ol[jq] = 0.f; orr[jq] = 0.f; }
  #pragma unroll
  for (int k = 0; k < 16; ++k) {
    float hv = hh[k];
    #pragma unroll
    for (int jq = 0; jq < 8; ++jq) {
      ol[jq]  = fmaf(hv, w2[k][jq], ol[jq]);
      orr[jq] = fmaf(hv, w2[k][8 + jq], orr[jq]);
    }
  }
  *(float4*)(xl2 + (size_t)n * 8)     = make_float4(ol[0], ol[1], ol[2], ol[3]);
  *(float4*)(xl2 + (size_t)n * 8 + 4) = make_float4(ol[4], ol[5], ol[6], ol[7]);
  *(float4*)(xr2 + (size_t)n * 8)     = make_float4(orr[0], orr[1], orr[2], orr[3]);
  *(float4*)(xr2 + (size_t)n * 8 + 4) = make_float4(orr[4], orr[5], orr[6], orr[7]);
}

// ---------------- Layer 2: warp-per-node; lane = (edge j<8, channel c<8) ----------------

__global__ __launch_bounds__(256) void k_l2(const float* __restrict__ xl2,
    const float* __restrict__ xr2, const float* __restrict__ a2,
    const float* __restrict__ b2, const int* __restrict__ rowstart,
    const int* __restrict__ cnt, const int* __restrict__ ssrc,
    float* __restrict__ out) {
  int tid = threadIdx.x;
  int i = (blockIdx.x * 256 + tid) >> 6;
  if (i >= NN) return;
  int lane = tid & 63;
  int j = lane >> 3, c = lane & 7;

  float xrc = xr2[(size_t)i * 8 + c];
  float avc = a2[c];
  int rs = rowstart[i], deg = cnt[i];

  float den = 0.f, accc = 0.f;
  for (int base = 0; base < deg; base += 8) {
    int jj = base + j;
    bool valid = jj < deg;
    int s = valid ? ssrc[rs + jj] : 0;
    float xlc = xl2[(size_t)s * 8 + c];
    float lg = lrelu(xlc + xrc) * avc;
    lg += __shfl_xor(lg, 1);
    lg += __shfl_xor(lg, 2);
    lg += __shfl_xor(lg, 4);
    float p = valid ? __expf(lg) : 0.f;
    den += p;
    accc = fmaf(p, xlc, accc);
  }
  #pragma unroll
  for (int st = 8; st <= 32; st <<= 1) {
    den  += __shfl_xor(den, st);
    accc += __shfl_xor(accc, st);
  }
  if (j == 0) {
    float v = accc / (den + 1e-16f) + b2[c];
    out[(size_t)i * 8 + c] = 1.f / (1.f + __expf(-v));
  }
}

// ---------------- launcher ----------------

extern "C" void kernel_launch(void* const* d_in, const int* in_sizes, int n_in,
                              void* d_out, int out_size, void* d_ws, size_t ws_size,
                              hipStream_t stream) {
  const float* x   = (const float*)d_in[0];
  const int*   ei  = (const int*)d_in[1];
  const float* W1l = (const float*)d_in[2];
  const float* W1r = (const float*)d_in[3];
  const float* a1  = (const float*)d_in[4];
  const float* b1  = (const float*)d_in[5];
  const float* W2l = (const float*)d_in[6];
  const float* W2r = (const float*)d_in[7];
  const float* a2  = (const float*)d_in[8];
  const float* b2  = (const float*)d_in[9];
  const int* src = ei;
  const int* dst = ei + NE;

  char* ws = (char*)d_ws;
  size_t off = 0;
  auto alloc = [&](size_t bytes) { void* p = (void*)(ws + off); off += (bytes + 255) & ~(size_t)255; return p; };
  unsigned* btot   = (unsigned*)alloc((size_t)NB * 4);
  unsigned* bstart = (unsigned*)alloc((size_t)(NB + 1) * 4);
  unsigned* bcur   = (unsigned*)alloc((size_t)NB * 4);
  int*      rowstart = (int*)alloc((size_t)NN * 4);
  int*      cnt      = (int*)alloc((size_t)NN * 4);
  int*      ssrc     = (int*)alloc((size_t)NE * 4);
  // abuf aliases xl1/xr1: abuf dead before k1_lin1 writes them
  char*     bigbase  = (char*)alloc((size_t)NN * 16 * 4 * 2);  // 12.8 MB
  unsigned* abuf = (unsigned*)bigbase;
  float*    xl1  = (float*)bigbase;
  float*    xr1  = (float*)(bigbase + (size_t)NN * 16 * 4);
  float*    xl2  = (float*)alloc((size_t)NN * 8 * 4);
  float*    xr2  = (float*)alloc((size_t)NN * 8 * 4);
  float*    hbuf = (float*)alloc((size_t)NN * 16 * 4);

  hipMemsetAsync(btot, 0, (size_t)NB * 4, stream);

  k_bhist<<<NBLK_A, 256, 0, stream>>>(dst, btot);
  k_bscan<<<1, 256, 0, stream>>>(btot, bstart, bcur);
  k_bin  <<<NBLK_A, 256, 0, stream>>>(src, dst, bcur, abuf);
  k_bsort<<<NB, 256, 0, stream>>>(bstart, abuf, rowstart, cnt, ssrc);

  k1_lin1<<<(NN + 255) / 256, 256, 0, stream>>>(x, W1l, W1r, xl1, xr1);

  int gw = (NN * 64 + 255) / 256;   // warp-per-node
  k_l1<<<gw, 256, 0, stream>>>(xl1, xr1, a1, b1, rowstart, cnt, ssrc, hbuf);
  k5_mid<<<(NN + 255) / 256, 256, 0, stream>>>(hbuf, W2l, W2r, xl2, xr2);
  k_l2<<<gw, 256, 0, stream>>>(xl2, xr2, a2, b2, rowstart, cnt, ssrc, (float*)d_out);
}